// Round 1
// 619.191 us; speedup vs baseline: 1.1517x; 1.1517x over previous
//
#include <hip/hip_runtime.h>
#include <hip/hip_bf16.h>
#include <stdint.h>

// x [4,2048,2048] fp32, W [8192,2048] fp32, gamma [2048] fp32 -> out [4,2048,8192] fp32
// C[M,N] = rmsnorm(x)[M,K] . Wq[N,K]^T * scale
#define M_ROWS 8192
#define K_DIM  2048
#define N_DIM  8192
#define W_ELEMS (N_DIM * K_DIM)
#define X_ELEMS (M_ROWS * K_DIM)
#define NT 32   // K_DIM / 64

typedef __bf16 v8bf __attribute__((ext_vector_type(8)));
typedef float  v4f  __attribute__((ext_vector_type(4)));

__device__ inline unsigned short f2bf(float f) {
  uint32_t u = __builtin_bit_cast(uint32_t, f);
  uint32_t r = (u + 0x7fffu + ((u >> 16) & 1u)) >> 16;
  return (unsigned short)r;
}

__device__ inline void async_copy16(const void* g, void* l) {
  __builtin_amdgcn_global_load_lds(
      (const __attribute__((address_space(1))) void*)g,
      (__attribute__((address_space(3))) void*)l, 16, 0, 0);
}

// ---------------- Kernel 1: sum(|W|), double accumulation ----------------
__global__ __launch_bounds__(256) void absum_kernel(const float* __restrict__ W,
                                                    double* __restrict__ out) {
  int tid = blockIdx.x * 256 + threadIdx.x;
  int stride = gridDim.x * 256;
  const float4* W4 = (const float4*)W;
  const int n4 = W_ELEMS / 4;
  double acc = 0.0;
  for (int i = tid; i < n4; i += stride) {
    float4 v = W4[i];
    acc += (double)fabsf(v.x) + (double)fabsf(v.y) +
           (double)fabsf(v.z) + (double)fabsf(v.w);
  }
  for (int off = 32; off > 0; off >>= 1) acc += __shfl_down(acc, off);
  __shared__ double wsum[4];
  int lane = threadIdx.x & 63, wid = threadIdx.x >> 6;
  if (lane == 0) wsum[wid] = acc;
  __syncthreads();
  if (threadIdx.x == 0) atomicAdd(out, wsum[0] + wsum[1] + wsum[2] + wsum[3]);
}

// ---------------- Kernel 2: RMSNorm row -> bf16 ----------------
__global__ __launch_bounds__(256) void rmsnorm_kernel(const float* __restrict__ X,
                                                      const float* __restrict__ gamma,
                                                      unsigned short* __restrict__ Xn) {
  const int row = blockIdx.x;
  const int t = threadIdx.x;
  const float4* xr = (const float4*)(X + (size_t)row * K_DIM);
  float4 a = xr[t * 2];
  float4 b = xr[t * 2 + 1];
  float ss = a.x * a.x + a.y * a.y + a.z * a.z + a.w * a.w +
             b.x * b.x + b.y * b.y + b.z * b.z + b.w * b.w;
  for (int off = 32; off > 0; off >>= 1) ss += __shfl_down(ss, off);
  __shared__ float wsum[4];
  int lane = t & 63, wid = t >> 6;
  if (lane == 0) wsum[wid] = ss;
  __syncthreads();
  float total = wsum[0] + wsum[1] + wsum[2] + wsum[3];
  float inv = 1.0f / sqrtf(total * (1.0f / (float)K_DIM) + 1e-6f);
  const float4* gr = (const float4*)gamma;
  float4 g0 = gr[t * 2];
  float4 g1 = gr[t * 2 + 1];
  union { unsigned short h[8]; uint4 u; } p;
  p.h[0] = f2bf((a.x * inv) * g0.x);
  p.h[1] = f2bf((a.y * inv) * g0.y);
  p.h[2] = f2bf((a.z * inv) * g0.z);
  p.h[3] = f2bf((a.w * inv) * g0.w);
  p.h[4] = f2bf((b.x * inv) * g1.x);
  p.h[5] = f2bf((b.y * inv) * g1.y);
  p.h[6] = f2bf((b.z * inv) * g1.z);
  p.h[7] = f2bf((b.w * inv) * g1.w);
  ((uint4*)(Xn + (size_t)row * K_DIM))[t] = p.u;
}

// ---------------- Kernel 3: ternary quantize W -> bf16 {-1,0,1} ----------------
__global__ __launch_bounds__(256) void quant_kernel(const float* __restrict__ W,
                                                    const double* __restrict__ sum_ws,
                                                    unsigned short* __restrict__ Wq) {
  float s = (float)fmax(sum_ws[0] * (1.0 / (double)W_ELEMS), 1e-5);
  size_t idx = ((size_t)blockIdx.x * 256 + threadIdx.x) * 8;
  const float4* w4 = (const float4*)(W + idx);
  float4 a = w4[0];
  float4 b = w4[1];
  union { unsigned short h[8]; uint4 u; } p;
  p.h[0] = f2bf(rintf(fminf(1.f, fmaxf(-1.f, a.x / s))));
  p.h[1] = f2bf(rintf(fminf(1.f, fmaxf(-1.f, a.y / s))));
  p.h[2] = f2bf(rintf(fminf(1.f, fmaxf(-1.f, a.z / s))));
  p.h[3] = f2bf(rintf(fminf(1.f, fmaxf(-1.f, a.w / s))));
  p.h[4] = f2bf(rintf(fminf(1.f, fmaxf(-1.f, b.x / s))));
  p.h[5] = f2bf(rintf(fminf(1.f, fmaxf(-1.f, b.y / s))));
  p.h[6] = f2bf(rintf(fminf(1.f, fmaxf(-1.f, b.z / s))));
  p.h[7] = f2bf(rintf(fminf(1.f, fmaxf(-1.f, b.w / s))));
  *(uint4*)(Wq + idx) = p.u;
}

// ---------------- Kernel 4: 256x256 tile, BK=64, 8-wave, 4-phase/K-tile,
// counted-vmcnt pipelined bf16 MFMA GEMM (m201-style template) ----------------
//
// LDS (128 KiB): A halves at [b*32768 + h*16384], B at +65536. Half-tile =
// 128 slots x 64 bf16 (16 KiB). A-half h slot (wm*64 + r) <-> block row
// wm*128 + h*64 + r; B-half h slot (wn*32 + r) <-> block N-row wn*64 + h*32 + r.
// So a phase (qm,qn) reads exactly A-half qm and B-half qn; halves retire at
// phase granularity, enabling stage-issue of tile t+2's Ah0/Bh0 into the
// CURRENT buffer during phases 2/3 (regions already consumed in phases 0/1).
// In-row XOR swizzle (proven 0-conflict): elem (slot,k) at byte
// slot*128 + (((k>>3)^(slot&7))<<4) + (k&7)*2; staging pre-swizzles the
// GLOBAL source colgroup, LDS dest stays linear (global_load_lds constraint).
//
// Stage issue order (per tile t): p0:Bh1[t+1] p1:Ah1[t+1] p2:Ah0[t+2] p3:Bh0[t+2].
// Uniform s_waitcnt vmcnt(8) at end of p0/p1/p3 leaves exactly 4 half-tile
// stages (8 global_load_lds) in flight and gates each region's first read.
// Tail tiles clamp the global SOURCE k-tile (dead LDS regions absorb garbage),
// keeping stage/vmcnt counts fully uniform. Raw s_barrier (no implicit
// vmcnt(0) drain) + setprio(1) around each 16-MFMA cluster.
__global__ __launch_bounds__(512, 2) void gemm_kernel(
    const unsigned short* __restrict__ A,   // x_norm bf16 [M,K]
    const unsigned short* __restrict__ B,   // wq bf16 [N,K]
    const double* __restrict__ sum_ws,
    float* __restrict__ C) {
  __shared__ __align__(16) char lds[131072];

  const int tid = threadIdx.x;
  const int lane = tid & 63;
  const int wave = tid >> 6;
  const int wm = wave & 1;    // M half: wave owns 128 rows
  const int wn = wave >> 1;   // N quarter: wave owns 64 cols

  // XCD-aware swizzle (1024 % 8 == 0) + 4x4 supertile: each XCD gets a
  // 4(M) x 32(N) tile stripe -> its 4 A-panels (4 MB) stay L2-resident.
  const int bid = blockIdx.x;
  const int swz = (bid & 7) * 128 + (bid >> 3);
  const int st = swz >> 4, wi = swz & 15;
  const int mb = (st >> 3) * 4 + (wi >> 2);
  const int nb = (st & 7) * 4 + (wi & 3);
  const int m0 = mb * 256;
  const int n0 = nb * 256;

  // staging constants: chunk = wave*2+j (0..15), lane writes chunk*1024 + lane*16
  const int srow3 = lane >> 3;                 // row within 8-row chunk
  const int scg = (lane & 7) ^ srow3;          // pre-swizzled source colgroup

  // frag-read constants
  const int aoff_a = wm * 8192 + (lane & 15) * 128;
  const int boff_b = wn * 4096 + (lane & 15) * 128;
  const int swzk0 = ((lane >> 4) ^ (lane & 7)) << 4;        // ksub 0
  const int swzk1 = ((4 + (lane >> 4)) ^ (lane & 7)) << 4;  // ksub 1

  v4f acc[8][4] = {};
  v8bf af[4][2];   // A frags for current qm (overwritten at p2)
  v8bf b0f[2][2];  // B frags qn=0, held whole K-tile
  v8bf b1f[2][2];  // B frags qn=1, held whole K-tile

#define STAGE_A(B_, H_, KT_) do {                                              \
    _Pragma("unroll")                                                          \
    for (int j = 0; j < 2; ++j) {                                              \
      const int chunk_ = wave * 2 + j;                                         \
      const int slot_ = chunk_ * 8 + srow3;                                    \
      const int row_ = ((slot_ >> 6) << 7) + ((H_) << 6) + (slot_ & 63);       \
      async_copy16(A + (size_t)(m0 + row_) * K_DIM + ((KT_) << 6) + (scg << 3),\
                   lds + (B_) * 32768 + (H_) * 16384 + chunk_ * 1024);         \
    } } while (0)

#define STAGE_B(B_, H_, KT_) do {                                              \
    _Pragma("unroll")                                                          \
    for (int j = 0; j < 2; ++j) {                                              \
      const int chunk_ = wave * 2 + j;                                         \
      const int slot_ = chunk_ * 8 + srow3;                                    \
      const int row_ = ((slot_ >> 5) << 6) + ((H_) << 5) + (slot_ & 31);       \
      async_copy16(B + (size_t)(n0 + row_) * K_DIM + ((KT_) << 6) + (scg << 3),\
                   lds + 65536 + (B_) * 32768 + (H_) * 16384 + chunk_ * 1024); \
    } } while (0)

#define LOADA(B_, QM_) do {                                                    \
    _Pragma("unroll")                                                          \
    for (int tm = 0; tm < 4; ++tm) {                                           \
      af[tm][0] = *(const v8bf*)(lds + (B_) * 32768 + (QM_) * 16384 +          \
                                 aoff_a + tm * 2048 + swzk0);                  \
      af[tm][1] = *(const v8bf*)(lds + (B_) * 32768 + (QM_) * 16384 +          \
                                 aoff_a + tm * 2048 + swzk1);                  \
    } } while (0)

#define LOADB(B_, QN_, DST) do {                                               \
    _Pragma("unroll")                                                          \
    for (int tn = 0; tn < 2; ++tn) {                                           \
      DST[tn][0] = *(const v8bf*)(lds + 65536 + (B_) * 32768 + (QN_) * 16384 + \
                                  boff_b + tn * 2048 + swzk0);                 \
      DST[tn][1] = *(const v8bf*)(lds + 65536 + (B_) * 32768 + (QN_) * 16384 + \
                                  boff_b + tn * 2048 + swzk1);                 \
    } } while (0)

#define MMAC(BF, QM_, QN_) do {                                                \
    _Pragma("unroll")                                                          \
    for (int ks = 0; ks < 2; ++ks)                                             \
    _Pragma("unroll")                                                          \
    for (int tm = 0; tm < 4; ++tm)                                             \
    _Pragma("unroll")                                                          \
    for (int tn = 0; tn < 2; ++tn)                                             \
      acc[(QM_) * 4 + tm][(QN_) * 2 + tn] =                                    \
          __builtin_amdgcn_mfma_f32_16x16x32_bf16(                             \
              BF[tn][ks], af[tm][ks],                                          \
              acc[(QM_) * 4 + tm][(QN_) * 2 + tn], 0, 0, 0);                   \
  } while (0)

#define BARRIER() __builtin_amdgcn_s_barrier()
#define VM8() asm volatile("s_waitcnt vmcnt(8)" ::: "memory")

#define TILE(T_, B_) do {                                                      \
    const int t1_ = ((T_) + 1 < NT) ? (T_) + 1 : NT - 1;                       \
    const int t2_ = ((T_) + 2 < NT) ? (T_) + 2 : NT - 1;                       \
    /* p0: (qm0,qn0) */                                                        \
    LOADA(B_, 0);                                                              \
    LOADB(B_, 0, b0f);                                                         \
    STAGE_B(1 - (B_), 1, t1_);                                                 \
    BARRIER();                                                                 \
    __builtin_amdgcn_s_setprio(1); MMAC(b0f, 0, 0);                            \
    __builtin_amdgcn_s_setprio(0);                                             \
    VM8(); BARRIER();                                                          \
    /* p1: (qm0,qn1) */                                                        \
    LOADB(B_, 1, b1f);                                                         \
    STAGE_A(1 - (B_), 1, t1_);                                                 \
    BARRIER();                                                                 \
    __builtin_amdgcn_s_setprio(1); MMAC(b1f, 0, 1);                            \
    __builtin_amdgcn_s_setprio(0);                                             \
    VM8(); BARRIER();                                                          \
    /* p2: (qm1,qn0) */                                                        \
    LOADA(B_, 1);                                                              \
    STAGE_A(B_, 0, t2_);                                                       \
    BARRIER();                                                                 \
    __builtin_amdgcn_s_setprio(1); MMAC(b0f, 1, 0);                            \
    __builtin_amdgcn_s_setprio(0);                                             \
    BARRIER();                                                                 \
    /* p3: (qm1,qn1) */                                                        \
    STAGE_B(B_, 0, t2_);                                                       \
    BARRIER();                                                                 \
    __builtin_amdgcn_s_setprio(1); MMAC(b1f, 1, 1);                            \
    __builtin_amdgcn_s_setprio(0);                                             \
    VM8(); BARRIER();                                                          \
  } while (0)

  // Prologue: issue order matches steady-state vmcnt accounting.
  STAGE_A(0, 0, 0);   // Ah0[0]
  STAGE_B(0, 0, 0);   // Bh0[0]
  STAGE_B(0, 1, 0);   // Bh1[0]
  STAGE_A(0, 1, 0);   // Ah1[0]
  STAGE_A(1, 0, 1);   // Ah0[1]
  STAGE_B(1, 0, 1);   // Bh0[1]
  VM8();              // Ah0[0]/Bh0[0] landed; 8 loads in flight
  BARRIER();

  for (int t = 0; t < NT; t += 2) {
    TILE(t, 0);
    TILE(t + 1, 1);
  }

  // Epilogue (verified layout: per acc[tm][tn], M = lane&15, N = (lane>>4)*4+reg)
  const float s = (float)fmax(sum_ws[0] * (1.0 / (double)W_ELEMS), 1e-5);
  const int mBase = m0 + wm * 128 + (lane & 15);
  const int nBase = n0 + wn * 64 + ((lane >> 4) << 2);
#pragma unroll
  for (int tm = 0; tm < 8; ++tm) {
#pragma unroll
    for (int tn = 0; tn < 4; ++tn) {
      float4 v;
      v.x = acc[tm][tn][0] * s;
      v.y = acc[tm][tn][1] * s;
      v.z = acc[tm][tn][2] * s;
      v.w = acc[tm][tn][3] * s;
      *(float4*)&C[(size_t)(mBase + tm * 16) * N_DIM + (nBase + tn * 16)] = v;
    }
  }

#undef STAGE_A
#undef STAGE_B
#undef LOADA
#undef LOADB
#undef MMAC
#undef BARRIER
#undef VM8
#undef TILE
}

extern "C" void kernel_launch(void* const* d_in, const int* in_sizes, int n_in,
                              void* d_out, int out_size, void* d_ws, size_t ws_size,
                              hipStream_t stream) {
  const float* x = (const float*)d_in[0];
  const float* w = (const float*)d_in[1];
  const float* gamma = (const float*)d_in[2];
  float* out = (float*)d_out;

  double* ws_sum = (double*)d_ws;
  unsigned short* xn = (unsigned short*)((char*)d_ws + 16);
  unsigned short* wq = (unsigned short*)((char*)d_ws + 16 + (size_t)X_ELEMS * 2);

  hipMemsetAsync(d_ws, 0, 16, stream);
  absum_kernel<<<2048, 256, 0, stream>>>(w, ws_sum);
  rmsnorm_kernel<<<M_ROWS, 256, 0, stream>>>(x, gamma, xn);
  quant_kernel<<<W_ELEMS / (256 * 8), 256, 0, stream>>>(w, ws_sum, wq);
  gemm_kernel<<<(M_ROWS / 256) * (N_DIM / 256), 512, 0, stream>>>(xn, wq, ws_sum, out);
}

// Round 3
// 611.530 us; speedup vs baseline: 1.1661x; 1.0125x over previous
//
#include <hip/hip_runtime.h>
#include <hip/hip_bf16.h>
#include <stdint.h>

// x [4,2048,2048] fp32, W [8192,2048] fp32, gamma [2048] fp32 -> out [4,2048,8192] fp32
// C[M,N] = rmsnorm(x)[M,K] . Wq[N,K]^T * scale
#define M_ROWS 8192
#define K_DIM  2048
#define N_DIM  8192
#define W_ELEMS (N_DIM * K_DIM)
#define X_ELEMS (M_ROWS * K_DIM)
#define NT 32          // K_DIM / 64
#define ABSUM_BLOCKS 256

typedef __bf16 v8bf __attribute__((ext_vector_type(8)));
typedef float  v4f  __attribute__((ext_vector_type(4)));

__device__ inline unsigned short f2bf(float f) {
  uint32_t u = __builtin_bit_cast(uint32_t, f);
  uint32_t r = (u + 0x7fffu + ((u >> 16) & 1u)) >> 16;
  return (unsigned short)r;
}

__device__ inline void async_copy16(const void* g, void* l) {
  __builtin_amdgcn_global_load_lds(
      (const __attribute__((address_space(1))) void*)g,
      (__attribute__((address_space(3))) void*)l, 16, 0, 0);
}

// ---------------- Kernel 1: fused prep ----------------
// blocks [0, ABSUM_BLOCKS): per-block partial sum(|W|) -> partials[pb] (NO atomics:
// 2048 same-address device-scope f64 atomicAdds serialize cross-XCD).
// blocks [ABSUM_BLOCKS, ABSUM_BLOCKS+M_ROWS): rmsnorm row -> bf16.
__global__ __launch_bounds__(256) void prep_kernel(const float* __restrict__ X,
                                                   const float* __restrict__ gamma,
                                                   const float* __restrict__ W,
                                                   unsigned short* __restrict__ Xn,
                                                   double* __restrict__ partials) {
  __shared__ double wsumd[4];
  __shared__ float wsumf[4];
  const int t = threadIdx.x;
  const int lane = t & 63, wid = t >> 6;

  if (blockIdx.x < ABSUM_BLOCKS) {
    const int pb = blockIdx.x;
    int tid = pb * 256 + t;
    const float4* W4 = (const float4*)W;
    const int n4 = W_ELEMS / 4;
    double acc = 0.0;
    for (int i = tid; i < n4; i += ABSUM_BLOCKS * 256) {
      float4 v = W4[i];
      acc += (double)fabsf(v.x) + (double)fabsf(v.y) +
             (double)fabsf(v.z) + (double)fabsf(v.w);
    }
    for (int off = 32; off > 0; off >>= 1) acc += __shfl_down(acc, off);
    if (lane == 0) wsumd[wid] = acc;
    __syncthreads();
    if (t == 0) partials[pb] = wsumd[0] + wsumd[1] + wsumd[2] + wsumd[3];
    return;
  }

  const int row = blockIdx.x - ABSUM_BLOCKS;
  const float4* xr = (const float4*)(X + (size_t)row * K_DIM);
  float4 a = xr[t * 2];
  float4 b = xr[t * 2 + 1];
  float ss = a.x * a.x + a.y * a.y + a.z * a.z + a.w * a.w +
             b.x * b.x + b.y * b.y + b.z * b.z + b.w * b.w;
  for (int off = 32; off > 0; off >>= 1) ss += __shfl_down(ss, off);
  if (lane == 0) wsumf[wid] = ss;
  __syncthreads();
  float total = wsumf[0] + wsumf[1] + wsumf[2] + wsumf[3];
  float inv = 1.0f / sqrtf(total * (1.0f / (float)K_DIM) + 1e-6f);
  const float4* gr = (const float4*)gamma;
  float4 g0 = gr[t * 2];
  float4 g1 = gr[t * 2 + 1];
  union { unsigned short h[8]; uint4 u; } p;
  p.h[0] = f2bf((a.x * inv) * g0.x);
  p.h[1] = f2bf((a.y * inv) * g0.y);
  p.h[2] = f2bf((a.z * inv) * g0.z);
  p.h[3] = f2bf((a.w * inv) * g0.w);
  p.h[4] = f2bf((b.x * inv) * g1.x);
  p.h[5] = f2bf((b.y * inv) * g1.y);
  p.h[6] = f2bf((b.z * inv) * g1.z);
  p.h[7] = f2bf((b.w * inv) * g1.w);
  ((uint4*)(Xn + (size_t)row * K_DIM))[t] = p.u;
}

// ---------------- Kernel 2: reduce partials -> float scale ----------------
__global__ __launch_bounds__(256) void reduce_kernel(const double* __restrict__ partials,
                                                     float* __restrict__ scale) {
  double v = partials[threadIdx.x];
  for (int off = 32; off > 0; off >>= 1) v += __shfl_down(v, off);
  __shared__ double ws[4];
  int lane = threadIdx.x & 63, wid = threadIdx.x >> 6;
  if (lane == 0) ws[wid] = v;
  __syncthreads();
  if (threadIdx.x == 0) {
    double total = ws[0] + ws[1] + ws[2] + ws[3];
    scale[0] = (float)fmax(total * (1.0 / (double)W_ELEMS), 1e-5);
  }
}

// ---------------- Kernel 3: ternary quantize W -> bf16 {-1,0,1} ----------------
__global__ __launch_bounds__(256) void quant_kernel(const float* __restrict__ W,
                                                    const float* __restrict__ scale,
                                                    unsigned short* __restrict__ Wq) {
  float s = scale[0];
  size_t idx = ((size_t)blockIdx.x * 256 + threadIdx.x) * 8;
  const float4* w4 = (const float4*)(W + idx);
  float4 a = w4[0];
  float4 b = w4[1];
  union { unsigned short h[8]; uint4 u; } p;
  p.h[0] = f2bf(rintf(fminf(1.f, fmaxf(-1.f, a.x / s))));
  p.h[1] = f2bf(rintf(fminf(1.f, fmaxf(-1.f, a.y / s))));
  p.h[2] = f2bf(rintf(fminf(1.f, fmaxf(-1.f, a.z / s))));
  p.h[3] = f2bf(rintf(fminf(1.f, fmaxf(-1.f, a.w / s))));
  p.h[4] = f2bf(rintf(fminf(1.f, fmaxf(-1.f, b.x / s))));
  p.h[5] = f2bf(rintf(fminf(1.f, fmaxf(-1.f, b.y / s))));
  p.h[6] = f2bf(rintf(fminf(1.f, fmaxf(-1.f, b.z / s))));
  p.h[7] = f2bf(rintf(fminf(1.f, fmaxf(-1.f, b.w / s))));
  *(uint4*)(Wq + idx) = p.u;
}

// ---------------- Kernel 4: 256x256 tile, BK=64, 8-wave, 4-phase/K-tile ----------------
// RACE FIX vs round 2: vmcnt is PER-WAVE, but each LDS region holds chunks staged
// by two waves. A read of staged data is only safe after VM8 -> BARRIER (all waves
// retired their loads). Round 2 issued the b0f preload BETWEEN VM8 and BARRIER
// (p3 + prologue) -> stale B fragments. Now: VM8(); BARRIER(); LOADB(b0f).
//
// Steady-state ledger (per wave, oldest->newest), entering tile t (buffer B_):
//   {Ah1[t](t-1 p0), Ah0[t+1](t-1 p2), Bh1[t+1](t-1 p2), Bh0[t+1](t-1 p3)} = 8.
// p1 VM8 retires Ah1[t] (read at p2); p3 VM8 retires Ah0/Bh1/Bh0[t+1] (read at
// p3-preload / t+1 p0 / t+1 p1). ds_read balance 8/4/8/4, 2 vmcnt waits/tile.
// WAR: every stage targets a region whose last ds_read completed (lgkm before the
// consuming MFMA) >=2 barriers earlier. Tail clamp re-writes identical data.
__global__ __launch_bounds__(512, 2) void gemm_kernel(
    const unsigned short* __restrict__ A,   // x_norm bf16 [M,K]
    const unsigned short* __restrict__ B,   // wq bf16 [N,K]
    const float* __restrict__ scale,
    float* __restrict__ C) {
  __shared__ __align__(16) char lds[131072];

  const int tid = threadIdx.x;
  const int lane = tid & 63;
  const int wave = tid >> 6;
  const int wm = wave & 1;    // M half: wave owns 128 rows
  const int wn = wave >> 1;   // N quarter: wave owns 64 cols

  // XCD-aware swizzle (1024 % 8 == 0) + 4x4 supertile
  const int bid = blockIdx.x;
  const int swz = (bid & 7) * 128 + (bid >> 3);
  const int st = swz >> 4, wi = swz & 15;
  const int mb = (st >> 3) * 4 + (wi >> 2);
  const int nb = (st & 7) * 4 + (wi & 3);
  const int m0 = mb * 256;
  const int n0 = nb * 256;

  const int srow3 = lane >> 3;
  const int scg = (lane & 7) ^ srow3;

  const int aoff_a = wm * 8192 + (lane & 15) * 128;
  const int boff_b = wn * 4096 + (lane & 15) * 128;
  const int swzk0 = ((lane >> 4) ^ (lane & 7)) << 4;
  const int swzk1 = ((4 + (lane >> 4)) ^ (lane & 7)) << 4;

  v4f acc[8][4] = {};
  v8bf af[4][2];
  v8bf b0f[2][2];
  v8bf b1f[2][2];

#define STAGE_A(B_, H_, KT_) do {                                              \
    _Pragma("unroll")                                                          \
    for (int j = 0; j < 2; ++j) {                                              \
      const int chunk_ = wave * 2 + j;                                         \
      const int slot_ = chunk_ * 8 + srow3;                                    \
      const int row_ = ((slot_ >> 6) << 7) + ((H_) << 6) + (slot_ & 63);       \
      async_copy16(A + (size_t)(m0 + row_) * K_DIM + ((KT_) << 6) + (scg << 3),\
                   lds + (B_) * 32768 + (H_) * 16384 + chunk_ * 1024);         \
    } } while (0)

#define STAGE_B(B_, H_, KT_) do {                                              \
    _Pragma("unroll")                                                          \
    for (int j = 0; j < 2; ++j) {                                              \
      const int chunk_ = wave * 2 + j;                                         \
      const int slot_ = chunk_ * 8 + srow3;                                    \
      const int row_ = ((slot_ >> 5) << 6) + ((H_) << 5) + (slot_ & 31);       \
      async_copy16(B + (size_t)(n0 + row_) * K_DIM + ((KT_) << 6) + (scg << 3),\
                   lds + 65536 + (B_) * 32768 + (H_) * 16384 + chunk_ * 1024); \
    } } while (0)

#define LOADA(B_, QM_) do {                                                    \
    _Pragma("unroll")                                                          \
    for (int tm = 0; tm < 4; ++tm) {                                           \
      af[tm][0] = *(const v8bf*)(lds + (B_) * 32768 + (QM_) * 16384 +          \
                                 aoff_a + tm * 2048 + swzk0);                  \
      af[tm][1] = *(const v8bf*)(lds + (B_) * 32768 + (QM_) * 16384 +          \
                                 aoff_a + tm * 2048 + swzk1);                  \
    } } while (0)

#define LOADB(B_, QN_, DST) do {                                               \
    _Pragma("unroll")                                                          \
    for (int tn = 0; tn < 2; ++tn) {                                           \
      DST[tn][0] = *(const v8bf*)(lds + 65536 + (B_) * 32768 + (QN_) * 16384 + \
                                  boff_b + tn * 2048 + swzk0);                 \
      DST[tn][1] = *(const v8bf*)(lds + 65536 + (B_) * 32768 + (QN_) * 16384 + \
                                  boff_b + tn * 2048 + swzk1);                 \
    } } while (0)

#define MMAC(BF, QM_, QN_) do {                                                \
    _Pragma("unroll")                                                          \
    for (int ks = 0; ks < 2; ++ks)                                             \
    _Pragma("unroll")                                                          \
    for (int tm = 0; tm < 4; ++tm)                                             \
    _Pragma("unroll")                                                          \
    for (int tn = 0; tn < 2; ++tn)                                             \
      acc[(QM_) * 4 + tm][(QN_) * 2 + tn] =                                    \
          __builtin_amdgcn_mfma_f32_16x16x32_bf16(                             \
              BF[tn][ks], af[tm][ks],                                          \
              acc[(QM_) * 4 + tm][(QN_) * 2 + tn], 0, 0, 0);                   \
  } while (0)

#define BARRIER() __builtin_amdgcn_s_barrier()
#define VM8() asm volatile("s_waitcnt vmcnt(8)" ::: "memory")

#define TILE(T_, B_) do {                                                      \
    const int t1_ = ((T_) + 1 < NT) ? (T_) + 1 : NT - 1;                       \
    const int t2_ = ((T_) + 2 < NT) ? (T_) + 2 : NT - 1;                       \
    /* p0: (qm0,qn0) — b0f preloaded last tile (post-VM8+barrier) */           \
    LOADA(B_, 0);                                                              \
    STAGE_A(1 - (B_), 1, t1_);                                                 \
    BARRIER();                                                                 \
    __builtin_amdgcn_s_setprio(1); MMAC(b0f, 0, 0);                            \
    __builtin_amdgcn_s_setprio(0);                                             \
    BARRIER();                                                                 \
    /* p1: (qm0,qn1) */                                                        \
    LOADB(B_, 1, b1f);                                                         \
    BARRIER();                                                                 \
    __builtin_amdgcn_s_setprio(1); MMAC(b1f, 0, 1);                            \
    __builtin_amdgcn_s_setprio(0);                                             \
    VM8(); BARRIER();                                                          \
    /* p2: (qm1,qn0) */                                                        \
    LOADA(B_, 1);                                                              \
    STAGE_A(B_, 0, t2_);                                                       \
    STAGE_B(B_, 1, t2_);                                                       \
    BARRIER();                                                                 \
    __builtin_amdgcn_s_setprio(1); MMAC(b0f, 1, 0);                            \
    __builtin_amdgcn_s_setprio(0);                                             \
    BARRIER();                                                                 \
    /* p3: (qm1,qn1); b0f preload AFTER VM8+BARRIER (race fix) */              \
    STAGE_B(B_, 0, t2_);                                                       \
    VM8(); BARRIER();                                                          \
    LOADB(1 - (B_), 0, b0f);                                                   \
    __builtin_amdgcn_s_setprio(1); MMAC(b1f, 1, 1);                            \
    __builtin_amdgcn_s_setprio(0);                                             \
    BARRIER();                                                                 \
  } while (0)

  // Prologue: stage order matches steady-state ledger.
  STAGE_A(0, 0, 0);   // Ah0[0]
  STAGE_B(0, 0, 0);   // Bh0[0]
  STAGE_B(0, 1, 0);   // Bh1[0]
  STAGE_A(0, 1, 0);   // Ah1[0]   (plays t-1 p0)
  STAGE_A(1, 0, 1);   // Ah0[1]   (t-1 p2)
  STAGE_B(1, 1, 1);   // Bh1[1]   (t-1 p2)
  STAGE_B(1, 0, 1);   // Bh0[1]   (t-1 p3)
  VM8();              // 14 -> 8: Ah0[0]/Bh0[0]/Bh1[0] landed (this wave)
  BARRIER();          // ...and all other waves' too (race fix)
  LOADB(0, 0, b0f);   // preload b0f for tile 0

  for (int t = 0; t < NT; t += 2) {
    TILE(t, 0);
    TILE(t + 1, 1);
  }

  // Epilogue (verified layout: per acc[tm][tn], M = lane&15, N = (lane>>4)*4+reg)
  const float s = scale[0];
  const int mBase = m0 + wm * 128 + (lane & 15);
  const int nBase = n0 + wn * 64 + ((lane >> 4) << 2);
#pragma unroll
  for (int tm = 0; tm < 8; ++tm) {
#pragma unroll
    for (int tn = 0; tn < 4; ++tn) {
      float4 v;
      v.x = acc[tm][tn][0] * s;
      v.y = acc[tm][tn][1] * s;
      v.z = acc[tm][tn][2] * s;
      v.w = acc[tm][tn][3] * s;
      *(float4*)&C[(size_t)(mBase + tm * 16) * N_DIM + (nBase + tn * 16)] = v;
    }
  }

#undef STAGE_A
#undef STAGE_B
#undef LOADA
#undef LOADB
#undef MMAC
#undef BARRIER
#undef VM8
#undef TILE
}

extern "C" void kernel_launch(void* const* d_in, const int* in_sizes, int n_in,
                              void* d_out, int out_size, void* d_ws, size_t ws_size,
                              hipStream_t stream) {
  const float* x = (const float*)d_in[0];
  const float* w = (const float*)d_in[1];
  const float* gamma = (const float*)d_in[2];
  float* out = (float*)d_out;

  // ws layout: [0,16): float scale; [16, 16+32MB): xn bf16; then wq bf16 (32MB).
  // partials (256 doubles) overlap the wq region — consumed by reduce_kernel
  // before quant_kernel overwrites it.
  float* scale_f = (float*)d_ws;
  unsigned short* xn = (unsigned short*)((char*)d_ws + 16);
  unsigned short* wq = (unsigned short*)((char*)d_ws + 16 + (size_t)X_ELEMS * 2);
  double* partials = (double*)wq;

  prep_kernel<<<ABSUM_BLOCKS + M_ROWS, 256, 0, stream>>>(x, gamma, w, xn, partials);
  reduce_kernel<<<1, 256, 0, stream>>>(partials, scale_f);
  quant_kernel<<<W_ELEMS / (256 * 8), 256, 0, stream>>>(w, scale_f, wq);
  gemm_kernel<<<(M_ROWS / 256) * (N_DIM / 256), 512, 0, stream>>>(xn, wq, scale_f, out);
}

// Round 5
// 605.582 us; speedup vs baseline: 1.1776x; 1.0098x over previous
//
#include <hip/hip_runtime.h>
#include <hip/hip_bf16.h>
#include <stdint.h>

// x [4,2048,2048] fp32, W [8192,2048] fp32, gamma [2048] fp32 -> out [4,2048,8192] fp32
// C[M,N] = rmsnorm(x)[M,K] . Wq[N,K]^T * scale
#define M_ROWS 8192
#define K_DIM  2048
#define N_DIM  8192
#define W_ELEMS (N_DIM * K_DIM)
#define X_ELEMS (M_ROWS * K_DIM)
#define NT 32          // K_DIM / 64
#define ABSUM_BLOCKS 256

typedef __bf16 v8bf __attribute__((ext_vector_type(8)));
typedef float  v4f  __attribute__((ext_vector_type(4)));

__device__ inline unsigned short f2bf(float f) {
  uint32_t u = __builtin_bit_cast(uint32_t, f);
  uint32_t r = (u + 0x7fffu + ((u >> 16) & 1u)) >> 16;
  return (unsigned short)r;
}

__device__ inline void async_copy16(const void* g, void* l) {
  __builtin_amdgcn_global_load_lds(
      (const __attribute__((address_space(1))) void*)g,
      (__attribute__((address_space(3))) void*)l, 16, 0, 0);
}

// ---------------- Kernel 1: fused prep ----------------
// blocks [0, ABSUM_BLOCKS): per-block partial sum(|W|) -> partials[pb].
// blocks [ABSUM_BLOCKS, ...): rmsnorm row -> bf16, fully-coalesced split-row
// loads/stores (xr[t], xr[t+256] — was stride-32B xr[2t], xr[2t+1]).
__global__ __launch_bounds__(256) void prep_kernel(const float* __restrict__ X,
                                                   const float* __restrict__ gamma,
                                                   const float* __restrict__ W,
                                                   unsigned short* __restrict__ Xn,
                                                   double* __restrict__ partials) {
  __shared__ double wsumd[4];
  __shared__ float wsumf[4];
  const int t = threadIdx.x;
  const int lane = t & 63, wid = t >> 6;

  if (blockIdx.x < ABSUM_BLOCKS) {
    const int pb = blockIdx.x;
    int tid = pb * 256 + t;
    const float4* W4 = (const float4*)W;
    const int n4 = W_ELEMS / 4;
    double acc = 0.0;
    for (int i = tid; i < n4; i += ABSUM_BLOCKS * 256) {
      float4 v = W4[i];
      acc += (double)fabsf(v.x) + (double)fabsf(v.y) +
             (double)fabsf(v.z) + (double)fabsf(v.w);
    }
    for (int off = 32; off > 0; off >>= 1) acc += __shfl_down(acc, off);
    if (lane == 0) wsumd[wid] = acc;
    __syncthreads();
    if (t == 0) partials[pb] = wsumd[0] + wsumd[1] + wsumd[2] + wsumd[3];
    return;
  }

  const int row = blockIdx.x - ABSUM_BLOCKS;
  const float4* xr = (const float4*)(X + (size_t)row * K_DIM);
  float4 a = xr[t];          // elems 4t..4t+3
  float4 b = xr[t + 256];    // elems 1024+4t..1024+4t+3
  float ss = a.x * a.x + a.y * a.y + a.z * a.z + a.w * a.w +
             b.x * b.x + b.y * b.y + b.z * b.z + b.w * b.w;
  for (int off = 32; off > 0; off >>= 1) ss += __shfl_down(ss, off);
  if (lane == 0) wsumf[wid] = ss;
  __syncthreads();
  float total = wsumf[0] + wsumf[1] + wsumf[2] + wsumf[3];
  float inv = 1.0f / sqrtf(total * (1.0f / (float)K_DIM) + 1e-6f);
  const float4* gr = (const float4*)gamma;
  float4 g0 = gr[t];
  float4 g1 = gr[t + 256];
  union { unsigned short h[4]; uint2 u; } pa, pb;
  pa.h[0] = f2bf((a.x * inv) * g0.x);
  pa.h[1] = f2bf((a.y * inv) * g0.y);
  pa.h[2] = f2bf((a.z * inv) * g0.z);
  pa.h[3] = f2bf((a.w * inv) * g0.w);
  pb.h[0] = f2bf((b.x * inv) * g1.x);
  pb.h[1] = f2bf((b.y * inv) * g1.y);
  pb.h[2] = f2bf((b.z * inv) * g1.z);
  pb.h[3] = f2bf((b.w * inv) * g1.w);
  uint2* orow = (uint2*)(Xn + (size_t)row * K_DIM);
  orow[t] = pa.u;
  orow[t + 256] = pb.u;
}

// ---------------- Kernel 2: reduce partials -> float scale ----------------
__global__ __launch_bounds__(256) void reduce_kernel(const double* __restrict__ partials,
                                                     float* __restrict__ scale) {
  double v = partials[threadIdx.x];
  for (int off = 32; off > 0; off >>= 1) v += __shfl_down(v, off);
  __shared__ double ws[4];
  int lane = threadIdx.x & 63, wid = threadIdx.x >> 6;
  if (lane == 0) ws[wid] = v;
  __syncthreads();
  if (threadIdx.x == 0) {
    double total = ws[0] + ws[1] + ws[2] + ws[3];
    scale[0] = (float)fmax(total * (1.0 / (double)W_ELEMS), 1e-5);
  }
}

// ---------------- Kernel 3: ternary quantize W -> bf16 {-1,0,1} ----------------
// Coalesced split-block pattern (W4[t], W4[t+256]); block covers 2048 elems.
__global__ __launch_bounds__(256) void quant_kernel(const float* __restrict__ W,
                                                    const float* __restrict__ scale,
                                                    unsigned short* __restrict__ Wq) {
  float s = scale[0];
  const int t = threadIdx.x;
  const float4* W4 = (const float4*)W + (size_t)blockIdx.x * 512;
  float4 a = W4[t];
  float4 b = W4[t + 256];
  union { unsigned short h[4]; uint2 u; } pa, pb;
  pa.h[0] = f2bf(rintf(fminf(1.f, fmaxf(-1.f, a.x / s))));
  pa.h[1] = f2bf(rintf(fminf(1.f, fmaxf(-1.f, a.y / s))));
  pa.h[2] = f2bf(rintf(fminf(1.f, fmaxf(-1.f, a.z / s))));
  pa.h[3] = f2bf(rintf(fminf(1.f, fmaxf(-1.f, a.w / s))));
  pb.h[0] = f2bf(rintf(fminf(1.f, fmaxf(-1.f, b.x / s))));
  pb.h[1] = f2bf(rintf(fminf(1.f, fmaxf(-1.f, b.y / s))));
  pb.h[2] = f2bf(rintf(fminf(1.f, fmaxf(-1.f, b.z / s))));
  pb.h[3] = f2bf(rintf(fminf(1.f, fmaxf(-1.f, b.w / s))));
  uint2* o = (uint2*)(Wq + (size_t)blockIdx.x * 2048);
  o[t] = pa.u;
  o[t + 256] = pb.u;
}

// ---------------- Kernel 4: 256x256 tile, BK=64, 8-wave, 4-phase/K-tile ----------------
// Schedule identical to the PASSING round-3 kernel (race-free, 2 vmcnt(8)/tile,
// ds_reads 8/4/8/4). Changes (mapping/epilogue only):
//  * XCD stripe halved: each XCD owns 2 M-rows x 32 N-cols (x2 halves) so its
//    A-working-set is 2 MB (was 4 MB = full L2 -> thrashed by streaming B + C;
//    FETCH_SIZE showed ~200 MB = A re-fetched per supertile column). A staying
//    L2-resident shortens the A-stage latency the vmcnt pipeline must hide.
//  * Non-temporal C stores: C is 256 MB write-once; nt keeps it from evicting
//    A (L2) and B (LLC).
__global__ __launch_bounds__(512, 2) void gemm_kernel(
    const unsigned short* __restrict__ A,   // x_norm bf16 [M,K]
    const unsigned short* __restrict__ B,   // wq bf16 [N,K]
    const float* __restrict__ scale,
    float* __restrict__ C) {
  __shared__ __align__(16) char lds[131072];

  const int tid = threadIdx.x;
  const int lane = tid & 63;
  const int wave = tid >> 6;
  const int wm = wave & 1;    // M half: wave owns 128 rows
  const int wn = wave >> 1;   // N quarter: wave owns 64 cols

  // Bijective XCD mapping: bid%8 = XCD (dispatch round-robin). Per XCD:
  // idx bits [6]=half (M offset 16 tiles), [5:3]=nb group, [2]=mb offset,
  // [1:0]=nb offset -> 2x4 supertiles swept along N.
  const int bid = blockIdx.x;
  const int xcd = bid & 7;
  const int idx = bid >> 3;            // 0..127
  const int half = idx >> 6;
  const int i6 = idx & 63;
  const int mb = xcd * 2 + half * 16 + ((i6 >> 2) & 1);
  const int nb = (i6 >> 3) * 4 + (i6 & 3);
  const int m0 = mb * 256;
  const int n0 = nb * 256;

  const int srow3 = lane >> 3;
  const int scg = (lane & 7) ^ srow3;

  const int aoff_a = wm * 8192 + (lane & 15) * 128;
  const int boff_b = wn * 4096 + (lane & 15) * 128;
  const int swzk0 = ((lane >> 4) ^ (lane & 7)) << 4;
  const int swzk1 = ((4 + (lane >> 4)) ^ (lane & 7)) << 4;

  v4f acc[8][4] = {};
  v8bf af[4][2];
  v8bf b0f[2][2];
  v8bf b1f[2][2];

#define STAGE_A(B_, H_, KT_) do {                                              \
    _Pragma("unroll")                                                          \
    for (int j = 0; j < 2; ++j) {                                              \
      const int chunk_ = wave * 2 + j;                                         \
      const int slot_ = chunk_ * 8 + srow3;                                    \
      const int row_ = ((slot_ >> 6) << 7) + ((H_) << 6) + (slot_ & 63);       \
      async_copy16(A + (size_t)(m0 + row_) * K_DIM + ((KT_) << 6) + (scg << 3),\
                   lds + (B_) * 32768 + (H_) * 16384 + chunk_ * 1024);         \
    } } while (0)

#define STAGE_B(B_, H_, KT_) do {                                              \
    _Pragma("unroll")                                                          \
    for (int j = 0; j < 2; ++j) {                                              \
      const int chunk_ = wave * 2 + j;                                         \
      const int slot_ = chunk_ * 8 + srow3;                                    \
      const int row_ = ((slot_ >> 5) << 6) + ((H_) << 5) + (slot_ & 31);       \
      async_copy16(B + (size_t)(n0 + row_) * K_DIM + ((KT_) << 6) + (scg << 3),\
                   lds + 65536 + (B_) * 32768 + (H_) * 16384 + chunk_ * 1024); \
    } } while (0)

#define LOADA(B_, QM_) do {                                                    \
    _Pragma("unroll")                                                          \
    for (int tm = 0; tm < 4; ++tm) {                                           \
      af[tm][0] = *(const v8bf*)(lds + (B_) * 32768 + (QM_) * 16384 +          \
                                 aoff_a + tm * 2048 + swzk0);                  \
      af[tm][1] = *(const v8bf*)(lds + (B_) * 32768 + (QM_) * 16384 +          \
                                 aoff_a + tm * 2048 + swzk1);                  \
    } } while (0)

#define LOADB(B_, QN_, DST) do {                                               \
    _Pragma("unroll")                                                          \
    for (int tn = 0; tn < 2; ++tn) {                                           \
      DST[tn][0] = *(const v8bf*)(lds + 65536 + (B_) * 32768 + (QN_) * 16384 + \
                                  boff_b + tn * 2048 + swzk0);                 \
      DST[tn][1] = *(const v8bf*)(lds + 65536 + (B_) * 32768 + (QN_) * 16384 + \
                                  boff_b + tn * 2048 + swzk1);                 \
    } } while (0)

#define MMAC(BF, QM_, QN_) do {                                                \
    _Pragma("unroll")                                                          \
    for (int ks = 0; ks < 2; ++ks)                                             \
    _Pragma("unroll")                                                          \
    for (int tm = 0; tm < 4; ++tm)                                             \
    _Pragma("unroll")                                                          \
    for (int tn = 0; tn < 2; ++tn)                                             \
      acc[(QM_) * 4 + tm][(QN_) * 2 + tn] =                                    \
          __builtin_amdgcn_mfma_f32_16x16x32_bf16(                             \
              BF[tn][ks], af[tm][ks],                                          \
              acc[(QM_) * 4 + tm][(QN_) * 2 + tn], 0, 0, 0);                   \
  } while (0)

#define BARRIER() __builtin_amdgcn_s_barrier()
#define VM8() asm volatile("s_waitcnt vmcnt(8)" ::: "memory")

#define TILE(T_, B_) do {                                                      \
    const int t1_ = ((T_) + 1 < NT) ? (T_) + 1 : NT - 1;                       \
    const int t2_ = ((T_) + 2 < NT) ? (T_) + 2 : NT - 1;                       \
    /* p0: (qm0,qn0) — b0f preloaded last tile (post-VM8+barrier) */           \
    LOADA(B_, 0);                                                              \
    STAGE_A(1 - (B_), 1, t1_);                                                 \
    BARRIER();                                                                 \
    __builtin_amdgcn_s_setprio(1); MMAC(b0f, 0, 0);                            \
    __builtin_amdgcn_s_setprio(0);                                             \
    BARRIER();                                                                 \
    /* p1: (qm0,qn1) */                                                        \
    LOADB(B_, 1, b1f);                                                         \
    BARRIER();                                                                 \
    __builtin_amdgcn_s_setprio(1); MMAC(b1f, 0, 1);                            \
    __builtin_amdgcn_s_setprio(0);                                             \
    VM8(); BARRIER();                                                          \
    /* p2: (qm1,qn0) */                                                        \
    LOADA(B_, 1);                                                              \
    STAGE_A(B_, 0, t2_);                                                       \
    STAGE_B(B_, 1, t2_);                                                       \
    BARRIER();                                                                 \
    __builtin_amdgcn_s_setprio(1); MMAC(b0f, 1, 0);                            \
    __builtin_amdgcn_s_setprio(0);                                             \
    BARRIER();                                                                 \
    /* p3: (qm1,qn1); b0f preload AFTER VM8+BARRIER */                         \
    STAGE_B(B_, 0, t2_);                                                       \
    VM8(); BARRIER();                                                          \
    LOADB(1 - (B_), 0, b0f);                                                   \
    __builtin_amdgcn_s_setprio(1); MMAC(b1f, 1, 1);                            \
    __builtin_amdgcn_s_setprio(0);                                             \
    BARRIER();                                                                 \
  } while (0)

  // Prologue: stage order matches steady-state ledger.
  STAGE_A(0, 0, 0);   // Ah0[0]
  STAGE_B(0, 0, 0);   // Bh0[0]
  STAGE_B(0, 1, 0);   // Bh1[0]
  STAGE_A(0, 1, 0);   // Ah1[0]   (plays t-1 p0)
  STAGE_A(1, 0, 1);   // Ah0[1]   (t-1 p2)
  STAGE_B(1, 1, 1);   // Bh1[1]   (t-1 p2)
  STAGE_B(1, 0, 1);   // Bh0[1]   (t-1 p3)
  VM8();              // 14 -> 8: Ah0[0]/Bh0[0]/Bh1[0] landed (this wave)
  BARRIER();          // ...and all other waves' too
  LOADB(0, 0, b0f);   // preload b0f for tile 0

  for (int t = 0; t < NT; t += 2) {
    TILE(t, 0);
    TILE(t + 1, 1);
  }

  // Epilogue (verified layout: per acc[tm][tn], M = lane&15, N = (lane>>4)*4+reg)
  const float s = scale[0];
  const int mBase = m0 + wm * 128 + (lane & 15);
  const int nBase = n0 + wn * 64 + ((lane >> 4) << 2);
#pragma unroll
  for (int tm = 0; tm < 8; ++tm) {
#pragma unroll
    for (int tn = 0; tn < 4; ++tn) {
      v4f v = acc[tm][tn] * s;
      __builtin_nontemporal_store(
          v, (v4f*)&C[(size_t)(mBase + tm * 16) * N_DIM + (nBase + tn * 16)]);
    }
  }

#undef STAGE_A
#undef STAGE_B
#undef LOADA
#undef LOADB
#undef MMAC
#undef BARRIER
#undef VM8
#undef TILE
}

extern "C" void kernel_launch(void* const* d_in, const int* in_sizes, int n_in,
                              void* d_out, int out_size, void* d_ws, size_t ws_size,
                              hipStream_t stream) {
  const float* x = (const float*)d_in[0];
  const float* w = (const float*)d_in[1];
  const float* gamma = (const float*)d_in[2];
  float* out = (float*)d_out;

  // ws layout: [0,16): float scale; [16, 16+32MB): xn bf16; then wq bf16 (32MB).
  // partials (256 doubles) overlap the wq region — consumed by reduce_kernel
  // before quant_kernel overwrites it.
  float* scale_f = (float*)d_ws;
  unsigned short* xn = (unsigned short*)((char*)d_ws + 16);
  unsigned short* wq = (unsigned short*)((char*)d_ws + 16 + (size_t)X_ELEMS * 2);
  double* partials = (double*)wq;

  prep_kernel<<<ABSUM_BLOCKS + M_ROWS, 256, 0, stream>>>(x, gamma, w, xn, partials);
  reduce_kernel<<<1, 256, 0, stream>>>(partials, scale_f);
  quant_kernel<<<W_ELEMS / 2048, 256, 0, stream>>>(w, scale_f, wq);
  gemm_kernel<<<(M_ROWS / 256) * (N_DIM / 256), 512, 0, stream>>>(xn, wq, scale_f, out);
}